// Round 11
// baseline (252.690 us; speedup 1.0000x reference)
//
#include <hip/hip_runtime.h>
#include <stdint.h>

#define S_LEN  1500
#define S_PAD  1536
#define BATCH  4
#define NSTATE 1024
#define NHEAD  16
#define HDIM   64
#define MROWS  6000   // BATCH * S_LEN
#define C1 0.180336879f   // 0.125 * log2(e)

typedef __attribute__((ext_vector_type(8)))  short short8;    // 8 bf16 = 4 VGPRs
typedef __attribute__((ext_vector_type(4)))  float floatx4;
typedef __attribute__((ext_vector_type(16))) float floatx16;

__device__ __forceinline__ unsigned short f2bf(float f) {
  union { float f; unsigned int u; } v; v.f = f;
  unsigned int r = v.u + 0x7fffu + ((v.u >> 16) & 1u);
  return (unsigned short)(r >> 16);
}

// async global->LDS, 16B per lane: lane i reads its own global addr, writes
// wave-uniform LDS base + i*16.
__device__ __forceinline__ void gld_lds16(const void* g, void* l) {
  __builtin_amdgcn_global_load_lds(
      (const __attribute__((address_space(1))) void*)g,
      (__attribute__((address_space(3))) void*)l, 16, 0, 0);
}

// ---------------------------------------------------------------------------
// fp32 -> bf16 for x + 4 weight matrices, one launch; tail blocks zero the
// Vt s-pad [1500,1536) (replaces the 12 MB hipMemsetAsync dispatch).
// ---------------------------------------------------------------------------
__global__ __launch_bounds__(256) void cvt_all(
    const float* __restrict__ x,  const float* __restrict__ Wq,
    const float* __restrict__ Wk, const float* __restrict__ Wv,
    const float* __restrict__ Wo, unsigned short* __restrict__ dst,
    unsigned short* __restrict__ vt)
{
  const size_t NX   = (size_t)MROWS * NSTATE;
  const size_t NTOT = NX + 4u * 1024u * 1024u;
  size_t e = ((size_t)blockIdx.x * 256 + threadIdx.x) * 4;
  if (e >= NTOT) {
    // pad-zero: 4096 rows (b,h,d) x 36 shorts at s in [1500,1536)
    size_t p = (e - NTOT) >> 2;          // thread index, 0..36863
    int row = (int)(p / 9);
    int off = (int)(p % 9) * 4;
    uint2 z; z.x = 0u; z.y = 0u;
    *(uint2*)&vt[(size_t)row * S_PAD + 1500 + off] = z;
    return;
  }
  const float* src; size_t off;
  if (e < NX) { src = x; off = e; }
  else {
    size_t t = e - NX;
    int wsel = (int)(t >> 20);           // NW = 2^20
    off = t & ((1u << 20) - 1);
    src = (wsel == 0) ? Wq : (wsel == 1) ? Wk : (wsel == 2) ? Wv : Wo;
  }
  float4 v = *(const float4*)(src + off);
  uint2 o;
  o.x = (unsigned int)f2bf(v.x) | ((unsigned int)f2bf(v.y) << 16);
  o.y = (unsigned int)f2bf(v.z) | ((unsigned int)f2bf(v.w) << 16);
  *(uint2*)(dst + e) = o;
}

// ---------------------------------------------------------------------------
// GEMM: Y[m,n] = (sum_k X[m,k]*W[n,k] + bias) * oscale; bf16 in, fp32 accum.
// 128x128 tile, 4 waves (wave tile 64x64 = 2x2 of 32x32). 32 K-steps of
// BK=32, 4 LDS slots (16 KB each, 64 KB total -> 2 blocks/CU), prefetch
// depth 3, COUNTED vmcnt (T4): per step {s_waitcnt vmcnt(8); raw s_barrier;
// sched_barrier(0); issue stage(t+3 -> slot (t+3)&3); compute slot t&3}.
// Loads stay in flight across barriers (never drained to 0 in-loop).
// WAR safe: slot (t+3)&3 = slot (t-1)&3, fully consumed by every wave
// before this step's barrier (MFMA's lgkmcnt precedes barrier in program
// order). Tail: vmcnt(4) at t=30, vmcnt(0) at t=31.
// Fragment/staging geometry identical to the proven R8 kernel.
// outmode: 0 = bf16 row-major, 1 = f32 row-major,
//          2 = Vt [b,h,d,s]: reg-quad = 4 consecutive s at one d -> 8-B
//              uint2 stores (4-aligned s, never crosses the 1500 batch edge).
// ---------------------------------------------------------------------------
__device__ __forceinline__ void gemm128_p4(
    const unsigned short* __restrict__ X,
    const unsigned short* __restrict__ W,
    const float* __restrict__ bias,
    void* __restrict__ Yv,
    int m0, int n0, float oscale, int outmode)
{
  __shared__ char SM[4 * 16384];   // slot s: A at s*16384, B at s*16384+8192

  const int tid  = threadIdx.x;
  const int lane = tid & 63;
  const int wid  = tid >> 6;
  const int wm   = (wid & 1) * 64;
  const int wn   = (wid >> 1) * 64;
  const int l31  = lane & 31;
  const int lhi  = lane >> 5;
  const int fr   = (l31 >> 1) & 3;     // read-side XOR (row-dependent bits)

  floatx16 acc[2][2];
#pragma unroll
  for (int i = 0; i < 2; ++i)
#pragma unroll
    for (int j = 0; j < 2; ++j)
      acc[i][j] = (floatx16)(0.f);

  const int srow = tid >> 2;                       // 0..63
  const int logc = (lane & 3) ^ ((srow >> 1) & 3); // pre-swizzled source chunk

  const char* xrp[2];
  const char* wrp[2];
#pragma unroll
  for (int r = 0; r < 2; ++r) {
    int arow = m0 + r * 64 + srow;
    if (arow > MROWS - 1) arow = MROWS - 1;
    xrp[r] = (const char*)X + (size_t)arow * NSTATE * 2 + logc * 16;
    int brow = n0 + r * 64 + srow;   // N=1024 always full
    wrp[r] = (const char*)W + (size_t)brow * NSTATE * 2 + logc * 16;
  }

  // stage K-step t (32 bf16 = 64 B per row) into slot si: 4 loads/thread
  auto stage = [&](int t, int si) {
    const int kb = t * 64;
    char* ab = SM + si * 16384;
    char* bb = ab + 8192;
    gld_lds16(xrp[0] + kb, ab + 0 * 4096 + wid * 1024);
    gld_lds16(xrp[1] + kb, ab + 1 * 4096 + wid * 1024);
    gld_lds16(wrp[0] + kb, bb + 0 * 4096 + wid * 1024);
    gld_lds16(wrp[1] + kb, bb + 1 * 4096 + wid * 1024);
  };

  // prologue: 3 stages in flight (12 outstanding loads/thread)
  stage(0, 0);
  stage(1, 1);
  stage(2, 2);

  for (int t = 0; t < 32; ++t) {
    // counted wait: slot t's 4 loads (issued 3 steps ago) must be done;
    // later stages stay in flight.
    if (t < 30)      asm volatile("s_waitcnt vmcnt(8)" ::: "memory");
    else if (t == 30) asm volatile("s_waitcnt vmcnt(4)" ::: "memory");
    else             asm volatile("s_waitcnt vmcnt(0)" ::: "memory");
    __builtin_amdgcn_s_barrier();          // all waves' slot-t writes visible
    __builtin_amdgcn_sched_barrier(0);     // fence: no ds_read hoisting above

    if (t < 29) stage(t + 3, (t + 3) & 3);

    const unsigned short* A = (const unsigned short*)(SM + (t & 3) * 16384);
    const unsigned short* B = (const unsigned short*)(SM + (t & 3) * 16384 + 8192);

    short8 af[2][2], bf[2][2];
#pragma unroll
    for (int mt = 0; mt < 2; ++mt)
#pragma unroll
      for (int kc = 0; kc < 2; ++kc) {
        int row  = wm + mt * 32 + l31;
        int phys = (kc * 2 + lhi) ^ fr;
        af[mt][kc] = *(const short8*)(A + row * 32 + phys * 8);
      }
#pragma unroll
    for (int nt = 0; nt < 2; ++nt)
#pragma unroll
      for (int kc = 0; kc < 2; ++kc) {
        int row  = wn + nt * 32 + l31;
        int phys = (kc * 2 + lhi) ^ fr;
        bf[nt][kc] = *(const short8*)(B + row * 32 + phys * 8);
      }
    __builtin_amdgcn_s_setprio(1);
#pragma unroll
    for (int mt = 0; mt < 2; ++mt)
#pragma unroll
      for (int nt = 0; nt < 2; ++nt)
#pragma unroll
        for (int kc = 0; kc < 2; ++kc)
          acc[mt][nt] = __builtin_amdgcn_mfma_f32_32x32x16_bf16(
              af[mt][kc], bf[nt][kc], acc[mt][nt], 0, 0, 0);
    __builtin_amdgcn_s_setprio(0);
  }

  // epilogue. 32x32 C/D: col = lane&31 (n), row = (r&3)+8*(r>>2)+4*lhi (m)
  if (outmode == 2) {
    // Vt[b, h, d, s]: lane's reg-quad rq = regs 4rq..4rq+3 = 4 consecutive s
    // (m rows 8rq+4lhi+0..3) at one d -> one 8-B store each.
    unsigned short* vt = (unsigned short*)Yv;
#pragma unroll
    for (int nt = 0; nt < 2; ++nt) {
      int ng = n0 + wn + nt * 32 + l31;
      float bias_v = bias[ng];
      int d  = ng & 63;
      int hh = ng >> 6;
#pragma unroll
      for (int mt = 0; mt < 2; ++mt)
#pragma unroll
        for (int rq = 0; rq < 4; ++rq) {
          int mgq = m0 + wm + mt * 32 + 8 * rq + 4 * lhi;
          if (mgq < MROWS) {
            int bb = mgq / 1500;
            int s0 = mgq - 1500 * bb;
            float v0 = acc[mt][nt][rq * 4 + 0] + bias_v;
            float v1 = acc[mt][nt][rq * 4 + 1] + bias_v;
            float v2 = acc[mt][nt][rq * 4 + 2] + bias_v;
            float v3 = acc[mt][nt][rq * 4 + 3] + bias_v;
            uint2 pk2;
            pk2.x = (unsigned int)f2bf(v0) | ((unsigned int)f2bf(v1) << 16);
            pk2.y = (unsigned int)f2bf(v2) | ((unsigned int)f2bf(v3) << 16);
            *(uint2*)&vt[(((size_t)bb * NHEAD + hh) * HDIM + d) * S_PAD + s0] = pk2;
          }
        }
    }
  } else {
#pragma unroll
    for (int nt = 0; nt < 2; ++nt) {
      int ng = n0 + wn + nt * 32 + l31;
      float bias_v = bias ? bias[ng] : 0.f;
#pragma unroll
      for (int mt = 0; mt < 2; ++mt)
#pragma unroll
        for (int r = 0; r < 16; ++r) {
          int mg = m0 + wm + mt * 32 + (r & 3) + 8 * (r >> 2) + 4 * lhi;
          if (mg < MROWS) {
            float val = (acc[mt][nt][r] + bias_v) * oscale;
            if (outmode == 1) ((float*)Yv)[(size_t)mg * NSTATE + ng] = val;
            else ((unsigned short*)Yv)[(size_t)mg * NSTATE + ng] = f2bf(val);
          }
        }
    }
  }
}

// 1D grid, XCD-chunked swizzle (1128 = 8*141, bijective), N fastest so
// consecutive blocks on one XCD share the same X row-panel in its L2.
__global__ __launch_bounds__(256) void proj_qkv(
    const unsigned short* __restrict__ X,
    const unsigned short* __restrict__ Wq, const unsigned short* __restrict__ Wk,
    const unsigned short* __restrict__ Wv,
    const float* __restrict__ bq, const float* __restrict__ bv,
    unsigned short* __restrict__ q, unsigned short* __restrict__ k,
    unsigned short* __restrict__ vt)
{
  const int id  = blockIdx.x;
  const int sid = (id & 7) * 141 + (id >> 3);
  const int z   = sid / 376;              // 47*8 blocks per matrix
  const int rem = sid - z * 376;
  const int m0  = (rem >> 3) * 128;
  const int n0  = (rem & 7) * 128;

  if (z == 0)      gemm128_p4(X, Wq, bq, q,  m0, n0, C1,  0);
  else if (z == 1) gemm128_p4(X, Wk, (const float*)nullptr, k, m0, n0, 1.0f, 0);
  else             gemm128_p4(X, Wv, bv, vt, m0, n0, 1.0f, 2);
}

__global__ __launch_bounds__(256) void proj_o(
    const unsigned short* __restrict__ X, const unsigned short* __restrict__ W,
    const float* __restrict__ bias, float* __restrict__ Y)
{
  const int id  = blockIdx.x;
  const int sid = (id & 7) * 47 + (id >> 3);   // 376 = 8*47, bijective
  gemm128_p4(X, W, bias, Y, (sid >> 3) * 128, (sid & 7) * 128, 1.0f, 1);
}

// ---------------------------------------------------------------------------
// Flash attention, transposed-score form (32x32x16 MFMA).
// Q pre-scaled by 0.125*log2(e) so P = exp2(S). P packed with
// v_cvt_pk_bf16_f32; cross-half exchange via v_permlane32_swap_b32.
// l computed on the MFMA pipe via all-ones A operand. Loop-invariant staging
// pointers; clamped last half-tile peeled.
// ---------------------------------------------------------------------------
#define NHALF 24   // 24 half-tiles of 64 kv = 1536 (S_PAD)

__global__ __launch_bounds__(256, 4) void attn32t(
    const unsigned short* __restrict__ Q, const unsigned short* __restrict__ K,
    const unsigned short* __restrict__ VT, unsigned short* __restrict__ O)
{
  __shared__ unsigned short SMEM[16384];      // 32 KB
  // K half-buffers at bytes bi*8192 ([64 kv][64 d], swizzled)
  // V half-buffers at bytes 16384 + bi*8192 ([64 d][64 kv], swizzled)
  unsigned short* Os = SMEM;                  // epilogue overlay [128 q][72]

  const int tid  = threadIdx.x;
  const int lane = tid & 63;
  const int w    = tid >> 6;
  const int l31  = lane & 31;
  const int lhi  = lane >> 5;

  // XCD-chunked swizzle (768 = 8*96): 12 consecutive blocks on one XCD share
  // the same (b,h) K/V panels in its private L2.
  const int id  = blockIdx.x;
  const int sid = (id & 7) * 96 + (id >> 3);
  const int qt  = sid % 12;
  const int hb  = sid / 12;
  const int h   = hb & 15;
  const int b   = hb >> 4;

  const size_t base  = ((size_t)b * S_LEN) * NSTATE + h * HDIM;
  const size_t vbase = (((size_t)b * NHEAD + h) * HDIM) * S_PAD;

  // staging indices (per thread, loop-invariant). row = w*16 + qq*8 + srow8,
  // so row&7 == srow8 and the swizzled chunk is qq/u-invariant.
  const int srow8 = lane >> 3;            // 0..7
  const int sc3   = lane & 7;
  const int swc   = sc3 ^ srow8;          // pre-swizzled source chunk

  const char* kq0 = (const char*)K +
      (base + (size_t)(w * 16 + srow8) * NSTATE + (size_t)swc * 8) * 2;
  const char* kq1 = kq0 + (size_t)8 * NSTATE * 2;
  const char* vq0 = (const char*)VT +
      (vbase + (size_t)(w * 16 + srow8) * S_PAD + (size_t)swc * 8) * 2;
  const char* vq1 = vq0 + (size_t)8 * S_PAD * 2;

  // Q fragments (B-operand): lane holds Q[q=l31][d = c*16 + lhi*8 + j]
  short8 qf[4];
  {
    int qrow = qt * 128 + w * 32 + l31;
    if (qrow > S_LEN - 1) qrow = S_LEN - 1;
    const unsigned short* qp = Q + base + (size_t)qrow * NSTATE;
#pragma unroll
    for (int c = 0; c < 4; ++c)
      qf[c] = *(const short8*)(qp + c * 16 + lhi * 8);
  }

  short8 ones8;
#pragma unroll
  for (int i = 0; i < 8; ++i) ones8[i] = (short)0x3F80;   // bf16 1.0

  floatx16 oacc[2];
  oacc[0] = (floatx16)(0.f);
  oacc[1] = (floatx16)(0.f);
  floatx16 lacc = (floatx16)(0.f);

  // unclamped stage of half u (valid for u <= 22: max row 22*64+63 < 1500)
  auto stageN = [&](int u, int bi) {
    char* kb = (char*)SMEM + bi * 8192;
    char* vb = (char*)SMEM + 16384 + bi * 8192;
    size_t ko = (size_t)u * (64 * NSTATE * 2);
    size_t vo = (size_t)u * (64 * 2);
    gld_lds16(kq0 + ko, kb + (w * 2 + 0) * 1024);
    gld_lds16(kq1 + ko, kb + (w * 2 + 1) * 1024);
    gld_lds16(vq0 + vo, vb + (w * 2 + 0) * 1024);
    gld_lds16(vq1 + vo, vb + (w * 2 + 1) * 1024);
  };
  // clamped stage of half 23 (kv rows 1472..1535 -> clamp to 1499)
  auto stageC = [&](int bi) {
    char* kb = (char*)SMEM + bi * 8192;
    char* vb = (char*)SMEM + 16384 + bi * 8192;
#pragma unroll
    for (int qq = 0; qq < 2; ++qq) {
      int s = 1472 + w * 16 + qq * 8 + srow8;
      if (s > S_LEN - 1) s = S_LEN - 1;
      gld_lds16((const char*)K + (base + (size_t)s * NSTATE + (size_t)swc * 8) * 2,
                kb + (w * 2 + qq) * 1024);
    }
    size_t vo = (size_t)23 * (64 * 2);
    gld_lds16(vq0 + vo, vb + (w * 2 + 0) * 1024);
    gld_lds16(vq1 + vo, vb + (w * 2 + 1) * 1024);
  };

  // prologue: stage half 0, wait
  stageN(0, 0);
  __syncthreads();

  for (int u = 0; u < NHALF; ++u) {
    const int cur = u & 1;
    if (u < NHALF - 2)       stageN(u + 1, cur ^ 1);
    else if (u == NHALF - 2) stageC(cur ^ 1);

    const unsigned short* Ks  = SMEM + cur * 4096;          // elements
    const unsigned short* Vts = SMEM + 8192 + cur * 4096;

#pragma unroll
    for (int kvt = 0; kvt < 2; ++kvt) {
      // --- S^T tile: 32 kv x 32 q (already in log2 units: Q pre-scaled) ---
      int row = kvt * 32 + l31;
      floatx16 sacc = (floatx16)(0.f);
      __builtin_amdgcn_s_setprio(1);
#pragma unroll
      for (int c = 0; c < 4; ++c) {
        int phys = (c * 2 + lhi) ^ (row & 7);
        short8 ak = *(const short8*)(Ks + row * 64 + phys * 8);
        sacc = __builtin_amdgcn_mfma_f32_32x32x16_bf16(ak, qf[c], sacc, 0, 0, 0);
      }
      __builtin_amdgcn_s_setprio(0);

      // kv masking (only the last half's tail: kv >= 1500)
      if (u == NHALF - 1) {
        if (kvt == 1) {
#pragma unroll
          for (int r = 0; r < 16; ++r) sacc[r] = -3.0e38f;
        } else {
          // kv = 1472 + local row; invalid local rows 28..31 (lhi=1, r=12..15)
#pragma unroll
          for (int r = 12; r < 16; ++r) sacc[r] = lhi ? -3.0e38f : sacc[r];
        }
      }

      // p = exp2(s); pack bf16 pairs with RNE (one cvt_pk per pair)
      unsigned int pk[8];
#pragma unroll
      for (int i = 0; i < 8; ++i) {
        float plo = exp2f(sacc[2 * i]);
        float phi = exp2f(sacc[2 * i + 1]);
        unsigned int rr;
        asm("v_cvt_pk_bf16_f32 %0, %1, %2" : "=v"(rr) : "v"(plo), "v"(phi));
        pk[i] = rr;
      }

      // cross-half exchange: permlane32_swap(a,b) -> a' = {lo:a, hi:b(lane-32)},
      // b' = {lo:a(lane+32), hi:b}.
      unsigned int a0 = pk[0], a1 = pk[1], b0 = pk[2], b1 = pk[3];
      asm("v_permlane32_swap_b32 %0, %1" : "+v"(a0), "+v"(b0));
      asm("v_permlane32_swap_b32 %0, %1" : "+v"(a1), "+v"(b1));
      unsigned int c0 = pk[4], c1 = pk[5], d0 = pk[6], d1 = pk[7];
      asm("v_permlane32_swap_b32 %0, %1" : "+v"(c0), "+v"(d0));
      asm("v_permlane32_swap_b32 %0, %1" : "+v"(c1), "+v"(d1));
      int4 f0i, f1i;
      f0i.x = a0; f0i.y = a1; f0i.z = b0; f0i.w = b1;
      f1i.x = c0; f1i.y = c1; f1i.z = d0; f1i.w = d1;
      short8 f0 = *(short8*)&f0i;
      short8 f1 = *(short8*)&f1i;

      __builtin_amdgcn_s_setprio(1);
      // l on the MFMA pipe: every row of (ones . P^T) is the full column sum
      lacc = __builtin_amdgcn_mfma_f32_32x32x16_bf16(ones8, f0, lacc, 0, 0, 0);
      lacc = __builtin_amdgcn_mfma_f32_32x32x16_bf16(ones8, f1, lacc, 0, 0, 0);

      // --- O^T += V^T P^T ---  (chunk8 idx within 64-kv half = kvt*4 + kc*2 + lhi)
#pragma unroll
      for (int dt = 0; dt < 2; ++dt) {
        int d = dt * 32 + l31;
        int p0 = ((kvt * 4 + 0) + lhi) ^ (d & 7);
        int p1 = ((kvt * 4 + 2) + lhi) ^ (d & 7);
        short8 av0 = *(const short8*)(Vts + d * 64 + p0 * 8);
        short8 av1 = *(const short8*)(Vts + d * 64 + p1 * 8);
        oacc[dt] = __builtin_amdgcn_mfma_f32_32x32x16_bf16(av0, f0, oacc[dt], 0, 0, 0);
        oacc[dt] = __builtin_amdgcn_mfma_f32_32x32x16_bf16(av1, f1, oacc[dt], 0, 0, 0);
      }
      __builtin_amdgcn_s_setprio(0);
    }

    __syncthreads();   // drains this iter's staging loads; syncs consumption
  }

  // lacc[0] = sum over ALL kv of the bf16 P used in PV (same for both halves)
  float inv = 1.f / lacc[0];

  // epilogue: O^T regs -> LDS transpose -> coalesced global store
  __syncthreads();   // everyone past the loop; SMEM reusable
#pragma unroll
  for (int dt = 0; dt < 2; ++dt)
#pragma unroll
    for (int g = 0; g < 4; ++g) {
      int d0 = dt * 32 + g * 8 + lhi * 4;
      float v0 = oacc[dt][4 * g + 0] * inv;
      float v1 = oacc[dt][4 * g + 1] * inv;
      float v2 = oacc[dt][4 * g + 2] * inv;
      float v3 = oacc[dt][4 * g + 3] * inv;
      uint2 pk2;
      pk2.x = (unsigned int)f2bf(v0) | ((unsigned int)f2bf(v1) << 16);
      pk2.y = (unsigned int)f2bf(v2) | ((unsigned int)f2bf(v3) << 16);
      *(uint2*)&Os[(w * 32 + l31) * 72 + d0] = pk2;
    }
  __syncthreads();
#pragma unroll
  for (int pass = 0; pass < 4; ++pass) {
    int e = pass * 256 + tid;
    int row = e >> 3, ch = e & 7;
    int s = qt * 128 + row;
    if (s < S_LEN)
      *(uint4*)&O[base + (size_t)s * NSTATE + ch * 8] = *(const uint4*)&Os[row * 72 + ch * 8];
  }
}

// ---------------------------------------------------------------------------
extern "C" void kernel_launch(void* const* d_in, const int* in_sizes, int n_in,
                              void* d_out, int out_size, void* d_ws, size_t ws_size,
                              hipStream_t stream) {
  const float* x  = (const float*)d_in[0];
  const float* Wq = (const float*)d_in[1];
  const float* bq = (const float*)d_in[2];
  const float* Wk = (const float*)d_in[3];
  const float* Wv = (const float*)d_in[4];
  const float* bv = (const float*)d_in[5];
  const float* Wo = (const float*)d_in[6];
  const float* bo = (const float*)d_in[7];
  float* out = (float*)d_out;

  const size_t NX  = (size_t)MROWS * NSTATE;
  const size_t NW  = (size_t)NSTATE * NSTATE;

  unsigned short* xb  = (unsigned short*)d_ws;   // dies after proj_qkv
  unsigned short* Wqb = xb  + NX;
  unsigned short* Wkb = Wqb + NW;
  unsigned short* Wvb = Wkb + NW;
  unsigned short* Wob = Wvb + NW;
  unsigned short* q   = Wob + NW;
  unsigned short* k   = q + NX;
  unsigned short* vt  = k + NX;
  unsigned short* wv  = xb;                      // alias onto dead xb

  const size_t n4_total = (NX + 4 * NW) / 4;     // -> 10096 blocks
  const int main_blocks = (int)(n4_total / 256);
  const int pad_blocks  = (BATCH * NHEAD * HDIM * 9) / 256;   // 144
  cvt_all<<<dim3(main_blocks + pad_blocks), dim3(256), 0, stream>>>(
      x, Wq, Wk, Wv, Wo, xb, vt);
  proj_qkv<<<dim3(1128), dim3(256), 0, stream>>>(xb, Wqb, Wkb, Wvb, bq, bv, q, k, vt);
  attn32t<<<dim3(768), dim3(256), 0, stream>>>(q, k, vt, wv);
  proj_o<<<dim3(376), dim3(256), 0, stream>>>(wv, Wob, bo, out);
}

// Round 12
// 237.713 us; speedup vs baseline: 1.0630x; 1.0630x over previous
//
#include <hip/hip_runtime.h>
#include <stdint.h>

#define S_LEN  1500
#define S_PAD  1536
#define BATCH  4
#define NSTATE 1024
#define NHEAD  16
#define HDIM   64
#define MROWS  6000   // BATCH * S_LEN
#define C1 0.180336879f   // 0.125 * log2(e)

typedef __attribute__((ext_vector_type(8)))  short short8;    // 8 bf16 = 4 VGPRs
typedef __attribute__((ext_vector_type(4)))  float floatx4;
typedef __attribute__((ext_vector_type(16))) float floatx16;

__device__ __forceinline__ unsigned short f2bf(float f) {
  union { float f; unsigned int u; } v; v.f = f;
  unsigned int r = v.u + 0x7fffu + ((v.u >> 16) & 1u);
  return (unsigned short)(r >> 16);
}

// async global->LDS, 16B per lane: lane i reads its own global addr, writes
// wave-uniform LDS base + i*16.
__device__ __forceinline__ void gld_lds16(const void* g, void* l) {
  __builtin_amdgcn_global_load_lds(
      (const __attribute__((address_space(1))) void*)g,
      (__attribute__((address_space(3))) void*)l, 16, 0, 0);
}

// ---------------------------------------------------------------------------
// fp32 -> bf16 for x + 4 weight matrices, one launch; tail blocks zero the
// Vt s-pad [1500,1536) (replaces the 12 MB hipMemsetAsync dispatch).
// ---------------------------------------------------------------------------
__global__ __launch_bounds__(256) void cvt_all(
    const float* __restrict__ x,  const float* __restrict__ Wq,
    const float* __restrict__ Wk, const float* __restrict__ Wv,
    const float* __restrict__ Wo, unsigned short* __restrict__ dst,
    unsigned short* __restrict__ vt)
{
  const size_t NX   = (size_t)MROWS * NSTATE;
  const size_t NTOT = NX + 4u * 1024u * 1024u;
  size_t e = ((size_t)blockIdx.x * 256 + threadIdx.x) * 4;
  if (e >= NTOT) {
    // pad-zero: 4096 rows (b,h,d) x 36 shorts at s in [1500,1536)
    size_t p = (e - NTOT) >> 2;          // thread index, 0..36863
    int row = (int)(p / 9);
    int off = (int)(p % 9) * 4;
    uint2 z; z.x = 0u; z.y = 0u;
    *(uint2*)&vt[(size_t)row * S_PAD + 1500 + off] = z;
    return;
  }
  const float* src; size_t off;
  if (e < NX) { src = x; off = e; }
  else {
    size_t t = e - NX;
    int wsel = (int)(t >> 20);           // NW = 2^20
    off = t & ((1u << 20) - 1);
    src = (wsel == 0) ? Wq : (wsel == 1) ? Wk : (wsel == 2) ? Wv : Wo;
  }
  float4 v = *(const float4*)(src + off);
  uint2 o;
  o.x = (unsigned int)f2bf(v.x) | ((unsigned int)f2bf(v.y) << 16);
  o.y = (unsigned int)f2bf(v.z) | ((unsigned int)f2bf(v.w) << 16);
  *(uint2*)(dst + e) = o;
}

// ---------------------------------------------------------------------------
// GEMM: Y[m,n] = (sum_k X[m,k]*W[n,k] + bias) * oscale; bf16 in, fp32 accum.
// 128x128 tile, 4 waves (wave tile 64x64 = 2x2 of 32x32); 16 K-steps of
// BK=64 as two BK=32 half-buffers, issue->drain->compute (R8 schedule: the
// measured optimum of this family — R9/R10/R11 pipelining variants all
// regressed; at 32 KB LDS ~4 resident blocks provide overlap for free).
// Chunk-XOR LDS swizzle. 32x32x16 MFMA.
// outmode: 0 = bf16 row-major, 1 = f32 row-major,
//          2 = Vt [b,h,d,s]: reg-quad = 4 consecutive s at one d -> 8-B
//              uint2 stores (4-aligned s, never crosses the 1500 batch edge).
// ---------------------------------------------------------------------------
__device__ __forceinline__ void gemm128_32(
    const unsigned short* __restrict__ X,
    const unsigned short* __restrict__ W,
    const float* __restrict__ bias,
    void* __restrict__ Yv,
    int m0, int n0, float oscale, int outmode)
{
  __shared__ unsigned short As[2][128 * 32];   // 8 KB each
  __shared__ unsigned short Bs[2][128 * 32];

  const int tid  = threadIdx.x;
  const int lane = tid & 63;
  const int wid  = tid >> 6;
  const int wm   = (wid & 1) * 64;
  const int wn   = (wid >> 1) * 64;
  const int l31  = lane & 31;
  const int lhi  = lane >> 5;
  const int fr   = (l31 >> 1) & 3;     // read-side XOR (row-dependent bits)

  floatx16 acc[2][2];
#pragma unroll
  for (int i = 0; i < 2; ++i)
#pragma unroll
    for (int j = 0; j < 2; ++j)
      acc[i][j] = (floatx16)(0.f);

  const int srow = tid >> 2;                       // 0..63
  const int logc = (lane & 3) ^ ((srow >> 1) & 3); // pre-swizzled source chunk

  const char* xrp[2];
  const char* wrp[2];
#pragma unroll
  for (int r = 0; r < 2; ++r) {
    int arow = m0 + r * 64 + srow;
    if (arow > MROWS - 1) arow = MROWS - 1;
    xrp[r] = (const char*)X + (size_t)arow * NSTATE * 2 + logc * 16;
    int brow = n0 + r * 64 + srow;   // N=1024 always full
    wrp[r] = (const char*)W + (size_t)brow * NSTATE * 2 + logc * 16;
  }

  for (int k0 = 0; k0 < NSTATE; k0 += 64) {
    __syncthreads();   // previous pair of half-tiles fully consumed
#pragma unroll
    for (int h = 0; h < 2; ++h) {
      int kb = (k0 + h * 32) * 2;    // byte offset along K
#pragma unroll
      for (int r = 0; r < 2; ++r) {
        gld_lds16(xrp[r] + kb, (char*)As[h] + r * 4096 + wid * 1024);
        gld_lds16(wrp[r] + kb, (char*)Bs[h] + r * 4096 + wid * 1024);
      }
    }
    __syncthreads();   // staging visible

#pragma unroll
    for (int h = 0; h < 2; ++h) {
      short8 af[2][2], bf[2][2];
#pragma unroll
      for (int mt = 0; mt < 2; ++mt)
#pragma unroll
        for (int kc = 0; kc < 2; ++kc) {
          int row  = wm + mt * 32 + l31;
          int phys = (kc * 2 + lhi) ^ fr;
          af[mt][kc] = *(const short8*)(As[h] + row * 32 + phys * 8);
        }
#pragma unroll
      for (int nt = 0; nt < 2; ++nt)
#pragma unroll
        for (int kc = 0; kc < 2; ++kc) {
          int row  = wn + nt * 32 + l31;
          int phys = (kc * 2 + lhi) ^ fr;
          bf[nt][kc] = *(const short8*)(Bs[h] + row * 32 + phys * 8);
        }
#pragma unroll
      for (int mt = 0; mt < 2; ++mt)
#pragma unroll
        for (int nt = 0; nt < 2; ++nt)
#pragma unroll
          for (int kc = 0; kc < 2; ++kc)
            acc[mt][nt] = __builtin_amdgcn_mfma_f32_32x32x16_bf16(
                af[mt][kc], bf[nt][kc], acc[mt][nt], 0, 0, 0);
    }
  }

  // epilogue. 32x32 C/D: col = lane&31 (n), row = (r&3)+8*(r>>2)+4*lhi (m)
  if (outmode == 2) {
    // Vt[b, h, d, s]: lane's reg-quad rq = regs 4rq..4rq+3 = 4 consecutive s
    // (m rows 8rq+4lhi+0..3) at one d -> one 8-B store each.
    unsigned short* vt = (unsigned short*)Yv;
#pragma unroll
    for (int nt = 0; nt < 2; ++nt) {
      int ng = n0 + wn + nt * 32 + l31;
      float bias_v = bias[ng];
      int d  = ng & 63;
      int hh = ng >> 6;
#pragma unroll
      for (int mt = 0; mt < 2; ++mt)
#pragma unroll
        for (int rq = 0; rq < 4; ++rq) {
          int mgq = m0 + wm + mt * 32 + 8 * rq + 4 * lhi;
          if (mgq < MROWS) {
            int bb = mgq / 1500;
            int s0 = mgq - 1500 * bb;
            float v0 = acc[mt][nt][rq * 4 + 0] + bias_v;
            float v1 = acc[mt][nt][rq * 4 + 1] + bias_v;
            float v2 = acc[mt][nt][rq * 4 + 2] + bias_v;
            float v3 = acc[mt][nt][rq * 4 + 3] + bias_v;
            uint2 pk2;
            pk2.x = (unsigned int)f2bf(v0) | ((unsigned int)f2bf(v1) << 16);
            pk2.y = (unsigned int)f2bf(v2) | ((unsigned int)f2bf(v3) << 16);
            *(uint2*)&vt[(((size_t)bb * NHEAD + hh) * HDIM + d) * S_PAD + s0] = pk2;
          }
        }
    }
  } else {
#pragma unroll
    for (int nt = 0; nt < 2; ++nt) {
      int ng = n0 + wn + nt * 32 + l31;
      float bias_v = bias ? bias[ng] : 0.f;
#pragma unroll
      for (int mt = 0; mt < 2; ++mt)
#pragma unroll
        for (int r = 0; r < 16; ++r) {
          int mg = m0 + wm + mt * 32 + (r & 3) + 8 * (r >> 2) + 4 * lhi;
          if (mg < MROWS) {
            float val = (acc[mt][nt][r] + bias_v) * oscale;
            if (outmode == 1) ((float*)Yv)[(size_t)mg * NSTATE + ng] = val;
            else ((unsigned short*)Yv)[(size_t)mg * NSTATE + ng] = f2bf(val);
          }
        }
    }
  }
}

// 1D grid, XCD-chunked swizzle (1128 = 8*141, bijective), N fastest so
// consecutive blocks on one XCD share the same X row-panel in its L2.
__global__ __launch_bounds__(256) void proj_qkv(
    const unsigned short* __restrict__ X,
    const unsigned short* __restrict__ Wq, const unsigned short* __restrict__ Wk,
    const unsigned short* __restrict__ Wv,
    const float* __restrict__ bq, const float* __restrict__ bv,
    unsigned short* __restrict__ q, unsigned short* __restrict__ k,
    unsigned short* __restrict__ vt)
{
  const int id  = blockIdx.x;
  const int sid = (id & 7) * 141 + (id >> 3);
  const int z   = sid / 376;              // 47*8 blocks per matrix
  const int rem = sid - z * 376;
  const int m0  = (rem >> 3) * 128;
  const int n0  = (rem & 7) * 128;

  if (z == 0)      gemm128_32(X, Wq, bq, q,  m0, n0, C1,  0);
  else if (z == 1) gemm128_32(X, Wk, (const float*)nullptr, k, m0, n0, 1.0f, 0);
  else             gemm128_32(X, Wv, bv, vt, m0, n0, 1.0f, 2);
}

__global__ __launch_bounds__(256) void proj_o(
    const unsigned short* __restrict__ X, const unsigned short* __restrict__ W,
    const float* __restrict__ bias, float* __restrict__ Y)
{
  const int id  = blockIdx.x;
  const int sid = (id & 7) * 47 + (id >> 3);   // 376 = 8*47, bijective
  gemm128_32(X, W, bias, Y, (sid >> 3) * 128, (sid & 7) * 128, 1.0f, 1);
}

// ---------------------------------------------------------------------------
// Flash attention, transposed-score form (32x32x16 MFMA).
// Q pre-scaled by 0.125*log2(e) so P = exp2(S). P packed with
// v_cvt_pk_bf16_f32; cross-half exchange via v_permlane32_swap_b32.
// l computed on the MFMA pipe via all-ones A operand. Loop-invariant staging
// pointers; clamped last half-tile peeled.
// ---------------------------------------------------------------------------
#define NHALF 24   // 24 half-tiles of 64 kv = 1536 (S_PAD)

__global__ __launch_bounds__(256, 4) void attn32t(
    const unsigned short* __restrict__ Q, const unsigned short* __restrict__ K,
    const unsigned short* __restrict__ VT, unsigned short* __restrict__ O)
{
  __shared__ unsigned short SMEM[16384];      // 32 KB
  // K half-buffers at bytes bi*8192 ([64 kv][64 d], swizzled)
  // V half-buffers at bytes 16384 + bi*8192 ([64 d][64 kv], swizzled)
  unsigned short* Os = SMEM;                  // epilogue overlay [128 q][72]

  const int tid  = threadIdx.x;
  const int lane = tid & 63;
  const int w    = tid >> 6;
  const int l31  = lane & 31;
  const int lhi  = lane >> 5;

  // XCD-chunked swizzle (768 = 8*96): 12 consecutive blocks on one XCD share
  // the same (b,h) K/V panels in its private L2.
  const int id  = blockIdx.x;
  const int sid = (id & 7) * 96 + (id >> 3);
  const int qt  = sid % 12;
  const int hb  = sid / 12;
  const int h   = hb & 15;
  const int b   = hb >> 4;

  const size_t base  = ((size_t)b * S_LEN) * NSTATE + h * HDIM;
  const size_t vbase = (((size_t)b * NHEAD + h) * HDIM) * S_PAD;

  // staging indices (per thread, loop-invariant). row = w*16 + qq*8 + srow8,
  // so row&7 == srow8 and the swizzled chunk is qq/u-invariant.
  const int srow8 = lane >> 3;            // 0..7
  const int sc3   = lane & 7;
  const int swc   = sc3 ^ srow8;          // pre-swizzled source chunk

  const char* kq0 = (const char*)K +
      (base + (size_t)(w * 16 + srow8) * NSTATE + (size_t)swc * 8) * 2;
  const char* kq1 = kq0 + (size_t)8 * NSTATE * 2;
  const char* vq0 = (const char*)VT +
      (vbase + (size_t)(w * 16 + srow8) * S_PAD + (size_t)swc * 8) * 2;
  const char* vq1 = vq0 + (size_t)8 * S_PAD * 2;

  // Q fragments (B-operand): lane holds Q[q=l31][d = c*16 + lhi*8 + j]
  short8 qf[4];
  {
    int qrow = qt * 128 + w * 32 + l31;
    if (qrow > S_LEN - 1) qrow = S_LEN - 1;
    const unsigned short* qp = Q + base + (size_t)qrow * NSTATE;
#pragma unroll
    for (int c = 0; c < 4; ++c)
      qf[c] = *(const short8*)(qp + c * 16 + lhi * 8);
  }

  short8 ones8;
#pragma unroll
  for (int i = 0; i < 8; ++i) ones8[i] = (short)0x3F80;   // bf16 1.0

  floatx16 oacc[2];
  oacc[0] = (floatx16)(0.f);
  oacc[1] = (floatx16)(0.f);
  floatx16 lacc = (floatx16)(0.f);

  // unclamped stage of half u (valid for u <= 22: max row 22*64+63 < 1500)
  auto stageN = [&](int u, int bi) {
    char* kb = (char*)SMEM + bi * 8192;
    char* vb = (char*)SMEM + 16384 + bi * 8192;
    size_t ko = (size_t)u * (64 * NSTATE * 2);
    size_t vo = (size_t)u * (64 * 2);
    gld_lds16(kq0 + ko, kb + (w * 2 + 0) * 1024);
    gld_lds16(kq1 + ko, kb + (w * 2 + 1) * 1024);
    gld_lds16(vq0 + vo, vb + (w * 2 + 0) * 1024);
    gld_lds16(vq1 + vo, vb + (w * 2 + 1) * 1024);
  };
  // clamped stage of half 23 (kv rows 1472..1535 -> clamp to 1499)
  auto stageC = [&](int bi) {
    char* kb = (char*)SMEM + bi * 8192;
    char* vb = (char*)SMEM + 16384 + bi * 8192;
#pragma unroll
    for (int qq = 0; qq < 2; ++qq) {
      int s = 1472 + w * 16 + qq * 8 + srow8;
      if (s > S_LEN - 1) s = S_LEN - 1;
      gld_lds16((const char*)K + (base + (size_t)s * NSTATE + (size_t)swc * 8) * 2,
                kb + (w * 2 + qq) * 1024);
    }
    size_t vo = (size_t)23 * (64 * 2);
    gld_lds16(vq0 + vo, vb + (w * 2 + 0) * 1024);
    gld_lds16(vq1 + vo, vb + (w * 2 + 1) * 1024);
  };

  // prologue: stage half 0, wait
  stageN(0, 0);
  __syncthreads();

  for (int u = 0; u < NHALF; ++u) {
    const int cur = u & 1;
    if (u < NHALF - 2)       stageN(u + 1, cur ^ 1);
    else if (u == NHALF - 2) stageC(cur ^ 1);

    const unsigned short* Ks  = SMEM + cur * 4096;          // elements
    const unsigned short* Vts = SMEM + 8192 + cur * 4096;

#pragma unroll
    for (int kvt = 0; kvt < 2; ++kvt) {
      // --- S^T tile: 32 kv x 32 q (already in log2 units: Q pre-scaled) ---
      int row = kvt * 32 + l31;
      floatx16 sacc = (floatx16)(0.f);
      __builtin_amdgcn_s_setprio(1);
#pragma unroll
      for (int c = 0; c < 4; ++c) {
        int phys = (c * 2 + lhi) ^ (row & 7);
        short8 ak = *(const short8*)(Ks + row * 64 + phys * 8);
        sacc = __builtin_amdgcn_mfma_f32_32x32x16_bf16(ak, qf[c], sacc, 0, 0, 0);
      }
      __builtin_amdgcn_s_setprio(0);

      // kv masking (only the last half's tail: kv >= 1500)
      if (u == NHALF - 1) {
        if (kvt == 1) {
#pragma unroll
          for (int r = 0; r < 16; ++r) sacc[r] = -3.0e38f;
        } else {
          // kv = 1472 + local row; invalid local rows 28..31 (lhi=1, r=12..15)
#pragma unroll
          for (int r = 12; r < 16; ++r) sacc[r] = lhi ? -3.0e38f : sacc[r];
        }
      }

      // p = exp2(s); pack bf16 pairs with RNE (one cvt_pk per pair)
      unsigned int pk[8];
#pragma unroll
      for (int i = 0; i < 8; ++i) {
        float plo = exp2f(sacc[2 * i]);
        float phi = exp2f(sacc[2 * i + 1]);
        unsigned int rr;
        asm("v_cvt_pk_bf16_f32 %0, %1, %2" : "=v"(rr) : "v"(plo), "v"(phi));
        pk[i] = rr;
      }

      // cross-half exchange: permlane32_swap(a,b) -> a' = {lo:a, hi:b(lane-32)},
      // b' = {lo:a(lane+32), hi:b}.
      unsigned int a0 = pk[0], a1 = pk[1], b0 = pk[2], b1 = pk[3];
      asm("v_permlane32_swap_b32 %0, %1" : "+v"(a0), "+v"(b0));
      asm("v_permlane32_swap_b32 %0, %1" : "+v"(a1), "+v"(b1));
      unsigned int c0 = pk[4], c1 = pk[5], d0 = pk[6], d1 = pk[7];
      asm("v_permlane32_swap_b32 %0, %1" : "+v"(c0), "+v"(d0));
      asm("v_permlane32_swap_b32 %0, %1" : "+v"(c1), "+v"(d1));
      int4 f0i, f1i;
      f0i.x = a0; f0i.y = a1; f0i.z = b0; f0i.w = b1;
      f1i.x = c0; f1i.y = c1; f1i.z = d0; f1i.w = d1;
      short8 f0 = *(short8*)&f0i;
      short8 f1 = *(short8*)&f1i;

      __builtin_amdgcn_s_setprio(1);
      // l on the MFMA pipe: every row of (ones . P^T) is the full column sum
      lacc = __builtin_amdgcn_mfma_f32_32x32x16_bf16(ones8, f0, lacc, 0, 0, 0);
      lacc = __builtin_amdgcn_mfma_f32_32x32x16_bf16(ones8, f1, lacc, 0, 0, 0);

      // --- O^T += V^T P^T ---  (chunk8 idx within 64-kv half = kvt*4 + kc*2 + lhi)
#pragma unroll
      for (int dt = 0; dt < 2; ++dt) {
        int d = dt * 32 + l31;
        int p0 = ((kvt * 4 + 0) + lhi) ^ (d & 7);
        int p1 = ((kvt * 4 + 2) + lhi) ^ (d & 7);
        short8 av0 = *(const short8*)(Vts + d * 64 + p0 * 8);
        short8 av1 = *(const short8*)(Vts + d * 64 + p1 * 8);
        oacc[dt] = __builtin_amdgcn_mfma_f32_32x32x16_bf16(av0, f0, oacc[dt], 0, 0, 0);
        oacc[dt] = __builtin_amdgcn_mfma_f32_32x32x16_bf16(av1, f1, oacc[dt], 0, 0, 0);
      }
      __builtin_amdgcn_s_setprio(0);
    }

    __syncthreads();   // drains this iter's staging loads; syncs consumption
  }

  // lacc[0] = sum over ALL kv of the bf16 P used in PV (same for both halves)
  float inv = 1.f / lacc[0];

  // epilogue: O^T regs -> LDS transpose -> coalesced global store
  __syncthreads();   // everyone past the loop; SMEM reusable
#pragma unroll
  for (int dt = 0; dt < 2; ++dt)
#pragma unroll
    for (int g = 0; g < 4; ++g) {
      int d0 = dt * 32 + g * 8 + lhi * 4;
      float v0 = oacc[dt][4 * g + 0] * inv;
      float v1 = oacc[dt][4 * g + 1] * inv;
      float v2 = oacc[dt][4 * g + 2] * inv;
      float v3 = oacc[dt][4 * g + 3] * inv;
      uint2 pk2;
      pk2.x = (unsigned int)f2bf(v0) | ((unsigned int)f2bf(v1) << 16);
      pk2.y = (unsigned int)f2bf(v2) | ((unsigned int)f2bf(v3) << 16);
      *(uint2*)&Os[(w * 32 + l31) * 72 + d0] = pk2;
    }
  __syncthreads();
#pragma unroll
  for (int pass = 0; pass < 4; ++pass) {
    int e = pass * 256 + tid;
    int row = e >> 3, ch = e & 7;
    int s = qt * 128 + row;
    if (s < S_LEN)
      *(uint4*)&O[base + (size_t)s * NSTATE + ch * 8] = *(const uint4*)&Os[row * 72 + ch * 8];
  }
}

// ---------------------------------------------------------------------------
extern "C" void kernel_launch(void* const* d_in, const int* in_sizes, int n_in,
                              void* d_out, int out_size, void* d_ws, size_t ws_size,
                              hipStream_t stream) {
  const float* x  = (const float*)d_in[0];
  const float* Wq = (const float*)d_in[1];
  const float* bq = (const float*)d_in[2];
  const float* Wk = (const float*)d_in[3];
  const float* Wv = (const float*)d_in[4];
  const float* bv = (const float*)d_in[5];
  const float* Wo = (const float*)d_in[6];
  const float* bo = (const float*)d_in[7];
  float* out = (float*)d_out;

  const size_t NX  = (size_t)MROWS * NSTATE;
  const size_t NW  = (size_t)NSTATE * NSTATE;

  unsigned short* xb  = (unsigned short*)d_ws;   // dies after proj_qkv
  unsigned short* Wqb = xb  + NX;
  unsigned short* Wkb = Wqb + NW;
  unsigned short* Wvb = Wkb + NW;
  unsigned short* Wob = Wvb + NW;
  unsigned short* q   = Wob + NW;
  unsigned short* k   = q + NX;
  unsigned short* vt  = k + NX;
  unsigned short* wv  = xb;                      // alias onto dead xb

  const size_t n4_total = (NX + 4 * NW) / 4;     // -> 10096 blocks
  const int main_blocks = (int)(n4_total / 256);
  const int pad_blocks  = (BATCH * NHEAD * HDIM * 9) / 256;   // 144
  cvt_all<<<dim3(main_blocks + pad_blocks), dim3(256), 0, stream>>>(
      x, Wq, Wk, Wv, Wo, xb, vt);
  proj_qkv<<<dim3(1128), dim3(256), 0, stream>>>(xb, Wqb, Wkb, Wvb, bq, bv, q, k, vt);
  attn32t<<<dim3(768), dim3(256), 0, stream>>>(q, k, vt, wv);
  proj_o<<<dim3(376), dim3(256), 0, stream>>>(wv, Wob, bo, out);
}